// Round 12
// baseline (354.827 us; speedup 1.0000x reference)
//
#include <hip/hip_runtime.h>

typedef __bf16 bf16x8 __attribute__((ext_vector_type(8)));
typedef float f32x4 __attribute__((ext_vector_type(4)));

#define T_LEN 200
#define NB 4096

__device__ __forceinline__ f32x4 mfma16(bf16x8 a, bf16x8 b, f32x4 c) {
    return __builtin_amdgcn_mfma_f32_16x16x32_bf16(a, b, c, 0, 0, 0);
}
// raw v_rcp_f32 (1 ulp) transcendentals; saturation exact (rcp(inf)=0)
__device__ __forceinline__ float sigf(float x) {
    return __builtin_amdgcn_rcpf(1.0f + __expf(-x));
}
__device__ __forceinline__ float tanh_fast(float x) {
    return 1.0f - 2.0f * __builtin_amdgcn_rcpf(__expf(2.0f * x) + 1.0f);
}

// ---- x staging split (trunc hi + fp32 remainder lo) ----
__device__ __forceinline__ unsigned pack2(float a, float b) {
    return (__float_as_uint(a) >> 16) | (__float_as_uint(b) & 0xFFFF0000u);
}
__device__ __forceinline__ float lo_of(float v) {
    return v - __uint_as_float(__float_as_uint(v) & 0xFFFF0000u);
}
// ---- RNE publish ----
__device__ __forceinline__ void publish(unsigned short* hp, unsigned short* lp, float v) {
    __bf16 h = (__bf16)v;
    *hp = __builtin_bit_cast(unsigned short, h);
    __bf16 l = (__bf16)(v - (float)h);
    *lp = __builtin_bit_cast(unsigned short, l);
}

struct Frag { bf16x8 hi, lo; };
__device__ __forceinline__ Frag make_frag(f32x4 a, f32x4 b) {
    Frag f;
    #pragma unroll
    for (int j = 0; j < 4; j++) {
        float v = a[j]; __bf16 h = (__bf16)v;
        f.hi[j] = h; f.lo[j] = (__bf16)(v - (float)h);
    }
    #pragma unroll
    for (int j = 0; j < 4; j++) {
        float v = b[j]; __bf16 h = (__bf16)v;
        f.hi[4 + j] = h; f.lo[4 + j] = (__bf16)(v - (float)h);
    }
    return f;
}
__device__ __forceinline__ bf16x8 load_w(const float* p) {   // W: bf16 RNE hi only
    f32x4 a = *(const f32x4*)p, b = *(const f32x4*)(p + 4);
    bf16x8 w;
    #pragma unroll
    for (int j = 0; j < 4; j++) { w[j] = (__bf16)a[j]; w[4 + j] = (__bf16)b[j]; }
    return w;
}
__device__ __forceinline__ f32x4 mm2(Frag a, bf16x8 w, f32x4 acc) {
    acc = mfma16(a.hi, w, acc);
    acc = mfma16(a.lo, w, acc);
    return acc;
}
__device__ __forceinline__ f32x4 mm3(Frag a, Frag b, f32x4 acc) {
    acc = mfma16(a.hi, b.hi, acc);
    acc = mfma16(a.hi, b.lo, acc);
    acc = mfma16(a.lo, b.hi, acc);
    return acc;
}

// 8 waves: 0-3 GRU (G), 4-7 AUGRU (A).
// Rebalanced pipeline. At real step t:
//   G S0(t): read hg(t-1) frags (sHG) + x(t) frags (sX); 24 MFMA gate-accs;
//            score(t-1) via 6 MFMA on hg(t-1) frags; wave wg0 writes a(t-1)=sig(score) -> sA
//   G S1(t): gating -> hg(t), publish sHG; stage x(t+1) -> sX
//   A S0(t): [t>0] read ha(t-2) frags (sHA); finish r/z(t-1); publish rh(t-1) -> sRH
//            x-parts of step t into fresh accs (12 MFMA)
//   A S1(t): [t>0] read rh(t-1) frags; finish h_hat(t-1); a(t-1) from sA; blend -> ha(t-1),
//            publish sHA; shift accs
// Hazards (producer -> consumer crosses >=1 barrier):
//   sX  : R(all) S0(t);  W(G) S1(t) [x(t+1)];  next R S0(t+1)
//   sHG : W(G) S1(t);    R(G) S0(t+1)
//   sA  : W(G) S0(t) [a(t-1)];  R(A) S1(t)
//   sHA : W(A) S1(t) [ha(t-1)]; R(A) S0(t+1)
//   sRH : W(A) S0(t) [rh(t-1)]; R(A) S1(t)
__global__ __launch_bounds__(512, 2)
void dien_fused(const int* __restrict__ u_idx, const int* __restrict__ i_idx,
                const int* __restrict__ seq, const float* __restrict__ item_emb,
                const float* __restrict__ user_bias, const float* __restrict__ item_bias,
                const float* __restrict__ gw_ih, const float* __restrict__ gb_ih,
                const float* __restrict__ gw_hh, const float* __restrict__ gb_hh,
                const float* __restrict__ attn_w, const float* __restrict__ attn_b,
                const float* __restrict__ wr_w, const float* __restrict__ wr_b,
                const float* __restrict__ wz_w, const float* __restrict__ wz_b,
                const float* __restrict__ wh_w, const float* __restrict__ wh_b,
                const float* __restrict__ aux_w, const float* __restrict__ aux_b,
                float* __restrict__ out)
{
    __shared__ int sSeq[16][T_LEN];
    __shared__ __align__(16) float sTP[16][64];
    __shared__ __align__(16) unsigned short sHGhi[16][72], sHGlo[16][72];
    __shared__ __align__(16) unsigned short sHAhi[16][72], sHAlo[16][72];
    __shared__ __align__(16) unsigned short sRHhi[16][72], sRHlo[16][72];
    __shared__ __align__(16) unsigned short sXhi[16][72],  sXlo[16][72];
    __shared__ float sA[16];
    __shared__ float sParts[16][4];

    const int tid  = threadIdx.x;
    const int wave = tid >> 6;           // 0..7
    const int lane = tid & 63;
    const int c    = lane & 15;
    const int q    = lane >> 4;
    const bool isG = (wave < 4);
    const int wg   = wave & 3;
    const int dglob = wg * 16 + c;
    const int row0 = blockIdx.x * 16;

    // ---- stage seq indices ----
    for (int i = tid; i < 16 * T_LEN; i += 512) {
        int b = i / T_LEN, t = i - b * T_LEN;
        sSeq[b][t] = seq[(row0 + b) * T_LEN + t];
    }

    // ---- fm1 ----
    if (tid < 16) {
        int b = row0 + tid;
        out[b] = user_bias[u_idx[b]] + item_bias[i_idx[b]];
    }

    // ---- target_proj (16x64 fp32), threads 0..255 ----
    if (tid < 256) {
        int b  = tid >> 4;
        int d0 = (tid & 15) * 4;
        const float* erow = item_emb + (long)i_idx[row0 + b] * 64;
        float e[64];
        #pragma unroll
        for (int k4 = 0; k4 < 16; k4++) {
            f32x4 v = *(const f32x4*)(erow + k4 * 4);
            #pragma unroll
            for (int j = 0; j < 4; j++) e[k4 * 4 + j] = v[j];
        }
        #pragma unroll
        for (int dd = 0; dd < 4; dd++) {
            int d = d0 + dd;
            const float* wrow = attn_w + d * 64;
            float s = attn_b[d];
            #pragma unroll
            for (int k4 = 0; k4 < 16; k4++) {
                f32x4 wv = *(const f32x4*)(wrow + k4 * 4);
                #pragma unroll
                for (int j = 0; j < 4; j++) s += e[k4 * 4 + j] * wv[j];
            }
            sTP[b][d] = s;
        }
    }

    // ---- zero hg & ha exchange buffers (both read at S0(0)/S0(1)) ----
    for (int i = tid; i < 16 * 72; i += 512) {
        sHAhi[0][i] = 0; sHAlo[0][i] = 0;
        sHGhi[0][i] = 0; sHGlo[0][i] = 0;
    }
    // ---- prime sX with x(0) (G waves) ----
    const int xrow = wg * 4 + (lane >> 4);   // producer row (G)
    const int xch  = lane & 15;              // 4-float chunk within row
    if (isG) {
        const float* p = item_emb + (long)seq[(row0 + xrow) * T_LEN + 0] * 64 + xch * 4;
        f32x4 v = *(const f32x4*)p;
        unsigned h01 = pack2(v[0], v[1]), h23 = pack2(v[2], v[3]);
        unsigned l01 = pack2(lo_of(v[0]), lo_of(v[1])), l23 = pack2(lo_of(v[2]), lo_of(v[3]));
        *(uint2*)&sXhi[xrow][xch * 4] = make_uint2(h01, h23);
        *(uint2*)&sXlo[xrow][xch * 4] = make_uint2(l01, l23);
    }
    __syncthreads();

    // ---- register-resident weights (bf16-hi RNE), unioned across groups ----
    // G: W[0..1]=wih_r, W[2..3]=wih_z, W[4..5]=wih_n, W[6..7]=whh_r, W[8..9]=whh_z, W[10..11]=whh_n
    // A: W[0..1]=wrx, W[2..3]=wrh, W[4..5]=wzx, W[6..7]=wzh, W[8..9]=whx, W[10..11]=whhat
    bf16x8 W[12];
    if (isG) {
        #pragma unroll
        for (int g = 0; g < 3; g++)
            #pragma unroll
            for (int s = 0; s < 2; s++) {
                W[g * 2 + s]     = load_w(gw_ih + (g * 64 + dglob) * 64 + s * 32 + q * 8);
                W[6 + g * 2 + s] = load_w(gw_hh + (g * 64 + dglob) * 64 + s * 32 + q * 8);
            }
    } else {
        #pragma unroll
        for (int s = 0; s < 2; s++) {
            const int fo = dglob * 128 + s * 32 + q * 8;
            W[0 + s]  = load_w(wr_w + fo);
            W[2 + s]  = load_w(wr_w + fo + 64);
            W[4 + s]  = load_w(wz_w + fo);
            W[6 + s]  = load_w(wz_w + fo + 64);
            W[8 + s]  = load_w(wh_w + fo);
            W[10 + s] = load_w(wh_w + fo + 64);
        }
    }

    float bA, bB, bC, bD;
    if (isG) {
        bA = gb_ih[dglob] + gb_hh[dglob];
        bB = gb_ih[64 + dglob] + gb_hh[64 + dglob];
        bC = gb_ih[128 + dglob];
        bD = gb_hh[128 + dglob];
    } else {
        bA = wr_b[dglob];
        bB = wz_b[dglob];
        bC = wh_b[dglob];
        bD = 0.0f;
    }
    const float auxwc = aux_w[dglob];

    // TP as B-fragment (G only), hi/lo
    Frag tpB0, tpB1;
    if (isG) {
        tpB0 = make_frag(*(const f32x4*)&sTP[c][q * 8], *(const f32x4*)&sTP[c][q * 8 + 4]);
        tpB1 = make_frag(*(const f32x4*)&sTP[c][32 + q * 8], *(const f32x4*)&sTP[c][32 + q * 8 + 4]);
    }

    // ---- state ----
    float hst[4] = {0.f, 0.f, 0.f, 0.f};   // G: hg(t-1); A: ha(t-2)
    f32x4 gR, gZ, gNX, gNH;                 // G accs, S0 -> S1
    f32x4 pAR, pAZ, pAH;                    // A accs for tau = t-1
    f32x4 nAR, nAZ, nAH;                    // A accs for tau = t
    float z_c[4];                           // A: z(t-1), S0 -> S1

    for (int t = 0; t < T_LEN; t++) {
        f32x4 xg;   // G: x(t+1), loaded S0, staged S1

        // ================= Section 0 =================
        Frag xA0, xA1;
        xA0.hi = *(const bf16x8*)&sXhi[c][q * 8];
        xA1.hi = *(const bf16x8*)&sXhi[c][32 + q * 8];
        xA0.lo = *(const bf16x8*)&sXlo[c][q * 8];
        xA1.lo = *(const bf16x8*)&sXlo[c][32 + q * 8];

        if (isG) {
            int tn = (t + 1 < T_LEN) ? t + 1 : t;
            xg = *(const f32x4*)(item_emb + (long)sSeq[xrow][tn] * 64 + xch * 4);

            Frag fr0, fr1;  // hg(t-1)
            fr0.hi = *(const bf16x8*)&sHGhi[c][q * 8];
            fr1.hi = *(const bf16x8*)&sHGhi[c][32 + q * 8];
            fr0.lo = *(const bf16x8*)&sHGlo[c][q * 8];
            fr1.lo = *(const bf16x8*)&sHGlo[c][32 + q * 8];

            // score(t-1) + a(t-1) (t=0 writes a from zero frags; never read)
            f32x4 sc = {0.f, 0.f, 0.f, 0.f};
            sc = mm3(fr0, tpB0, sc);
            sc = mm3(fr1, tpB1, sc);
            if (wg == 0 && (c >> 2) == q) {
                int i = c & 3;
                float d = (i == 0) ? sc[0] : (i == 1) ? sc[1] : (i == 2) ? sc[2] : sc[3];
                sA[c] = sigf(d);
            }

            gR = (f32x4){bA, bA, bA, bA};
            gR = mm2(xA0, W[0], gR); gR = mm2(xA1, W[1], gR);
            gR = mm2(fr0, W[6], gR); gR = mm2(fr1, W[7], gR);
            gZ = (f32x4){bB, bB, bB, bB};
            gZ = mm2(xA0, W[2], gZ); gZ = mm2(xA1, W[3], gZ);
            gZ = mm2(fr0, W[8], gZ); gZ = mm2(fr1, W[9], gZ);
            gNX = (f32x4){bC, bC, bC, bC};
            gNX = mm2(xA0, W[4], gNX); gNX = mm2(xA1, W[5], gNX);
            gNH = (f32x4){bD, bD, bD, bD};
            gNH = mm2(fr0, W[10], gNH); gNH = mm2(fr1, W[11], gNH);
        } else {
            if (t > 0) {
                Frag ha0, ha1;  // ha(t-2)
                ha0.hi = *(const bf16x8*)&sHAhi[c][q * 8];
                ha1.hi = *(const bf16x8*)&sHAhi[c][32 + q * 8];
                ha0.lo = *(const bf16x8*)&sHAlo[c][q * 8];
                ha1.lo = *(const bf16x8*)&sHAlo[c][32 + q * 8];
                pAR = mm2(ha0, W[2], pAR); pAR = mm2(ha1, W[3], pAR);
                pAZ = mm2(ha0, W[6], pAZ); pAZ = mm2(ha1, W[7], pAZ);
                #pragma unroll
                for (int i = 0; i < 4; i++) {
                    float r = sigf(pAR[i]);
                    z_c[i]  = sigf(pAZ[i]);
                    float rh = r * hst[i];     // hst = ha(t-2)
                    int rr = q * 4 + i;
                    publish(&sRHhi[rr][dglob], &sRHlo[rr][dglob], rh);
                }
            }
            // x-parts of step t
            nAR = (f32x4){bA, bA, bA, bA};
            nAR = mm2(xA0, W[0], nAR); nAR = mm2(xA1, W[1], nAR);
            nAZ = (f32x4){bB, bB, bB, bB};
            nAZ = mm2(xA0, W[4], nAZ); nAZ = mm2(xA1, W[5], nAZ);
            nAH = (f32x4){bC, bC, bC, bC};
            nAH = mm2(xA0, W[8], nAH); nAH = mm2(xA1, W[9], nAH);
        }

        __syncthreads();  // b_mid

        // ================= Section 1 =================
        if (isG) {
            #pragma unroll
            for (int i = 0; i < 4; i++) {
                float r = sigf(gR[i]);
                float z = sigf(gZ[i]);
                float n = tanh_fast(gNX[i] + r * gNH[i]);
                float hn = n + z * (hst[i] - n);
                hst[i] = hn;
                int rr = q * 4 + i;
                publish(&sHGhi[rr][dglob], &sHGlo[rr][dglob], hn);
            }
            // stage x(t+1) pre-split into sX
            unsigned h01 = pack2(xg[0], xg[1]), h23 = pack2(xg[2], xg[3]);
            unsigned l01 = pack2(lo_of(xg[0]), lo_of(xg[1]));
            unsigned l23 = pack2(lo_of(xg[2]), lo_of(xg[3]));
            *(uint2*)&sXhi[xrow][xch * 4] = make_uint2(h01, h23);
            *(uint2*)&sXlo[xrow][xch * 4] = make_uint2(l01, l23);
        } else {
            if (t > 0) {
                Frag rh0, rh1;  // rh(t-1)
                rh0.hi = *(const bf16x8*)&sRHhi[c][q * 8];
                rh1.hi = *(const bf16x8*)&sRHhi[c][32 + q * 8];
                rh0.lo = *(const bf16x8*)&sRHlo[c][q * 8];
                rh1.lo = *(const bf16x8*)&sRHlo[c][32 + q * 8];
                pAH = mm2(rh0, W[10], pAH); pAH = mm2(rh1, W[11], pAH);
                #pragma unroll
                for (int i = 0; i < 4; i++) {
                    int rr = q * 4 + i;
                    float a = sA[rr];
                    float hh = tanh_fast(pAH[i]);
                    float zz = a * z_c[i];
                    float hv = hst[i] + zz * (hh - hst[i]);
                    hst[i] = hv;                // ha(t-1)
                    publish(&sHAhi[rr][dglob], &sHAlo[rr][dglob], hv);
                }
            }
            pAR = nAR; pAZ = nAZ; pAH = nAH;
        }

        __syncthreads();  // b_end
    }

    // ---- epilogue: one extra half-step for tau = T-1 ----
    if (isG) {
        Frag fr0, fr1;  // hg(T-1)
        fr0.hi = *(const bf16x8*)&sHGhi[c][q * 8];
        fr1.hi = *(const bf16x8*)&sHGhi[c][32 + q * 8];
        fr0.lo = *(const bf16x8*)&sHGlo[c][q * 8];
        fr1.lo = *(const bf16x8*)&sHGlo[c][32 + q * 8];
        f32x4 sc = {0.f, 0.f, 0.f, 0.f};
        sc = mm3(fr0, tpB0, sc);
        sc = mm3(fr1, tpB1, sc);
        if (wg == 0 && (c >> 2) == q) {
            int i = c & 3;
            float d = (i == 0) ? sc[0] : (i == 1) ? sc[1] : (i == 2) ? sc[2] : sc[3];
            sA[c] = sigf(d);
        }
    } else {
        Frag ha0, ha1;  // ha(T-2)
        ha0.hi = *(const bf16x8*)&sHAhi[c][q * 8];
        ha1.hi = *(const bf16x8*)&sHAhi[c][32 + q * 8];
        ha0.lo = *(const bf16x8*)&sHAlo[c][q * 8];
        ha1.lo = *(const bf16x8*)&sHAlo[c][32 + q * 8];
        pAR = mm2(ha0, W[2], pAR); pAR = mm2(ha1, W[3], pAR);
        pAZ = mm2(ha0, W[6], pAZ); pAZ = mm2(ha1, W[7], pAZ);
        #pragma unroll
        for (int i = 0; i < 4; i++) {
            float r = sigf(pAR[i]);
            z_c[i]  = sigf(pAZ[i]);
            float rh = r * hst[i];
            int rr = q * 4 + i;
            publish(&sRHhi[rr][dglob], &sRHlo[rr][dglob], rh);
        }
    }
    __syncthreads();
    if (!isG) {
        Frag rh0, rh1;
        rh0.hi = *(const bf16x8*)&sRHhi[c][q * 8];
        rh1.hi = *(const bf16x8*)&sRHhi[c][32 + q * 8];
        rh0.lo = *(const bf16x8*)&sRHlo[c][q * 8];
        rh1.lo = *(const bf16x8*)&sRHlo[c][32 + q * 8];
        pAH = mm2(rh0, W[10], pAH); pAH = mm2(rh1, W[11], pAH);
        #pragma unroll
        for (int i = 0; i < 4; i++) {
            int rr = q * 4 + i;
            float a = sA[rr];
            float hh = tanh_fast(pAH[i]);
            float zz = a * z_c[i];
            float hv = hst[i] + zz * (hh - hst[i]);
            out[NB + (row0 + rr) * 64 + dglob] = hv;
        }
    }

    // ---- aux_logits from hg(T-1) (G group) ----
    if (isG) {
        float pa[4];
        #pragma unroll
        for (int i = 0; i < 4; i++) pa[i] = hst[i] * auxwc;
        #pragma unroll
        for (int m = 1; m < 16; m <<= 1) {
            #pragma unroll
            for (int i = 0; i < 4; i++) pa[i] += __shfl_xor(pa[i], m, 64);
        }
        if (c == 0) {
            #pragma unroll
            for (int i = 0; i < 4; i++) sParts[q * 4 + i][wg] = pa[i];
        }
    }
    __syncthreads();
    if (tid < 16) {
        out[NB + NB * 64 + row0 + tid] =
            sParts[tid][0] + sParts[tid][1] + sParts[tid][2] + sParts[tid][3] + aux_b[0];
    }
}

extern "C" void kernel_launch(void* const* d_in, const int* in_sizes, int n_in,
                              void* d_out, int out_size, void* d_ws, size_t ws_size,
                              hipStream_t stream) {
    dien_fused<<<dim3(256), dim3(512), 0, stream>>>(
        (const int*)d_in[0],      // u_idx
        (const int*)d_in[1],      // i_idx
        (const int*)d_in[2],      // seq
        (const float*)d_in[3],    // item_emb
        (const float*)d_in[4],    // user_bias
        (const float*)d_in[5],    // item_bias
        (const float*)d_in[6],    // gru_w_ih
        (const float*)d_in[7],    // gru_b_ih
        (const float*)d_in[8],    // gru_w_hh
        (const float*)d_in[9],    // gru_b_hh
        (const float*)d_in[10],   // attn_w
        (const float*)d_in[11],   // attn_b
        (const float*)d_in[12],   // wr_w
        (const float*)d_in[13],   // wr_b
        (const float*)d_in[14],   // wz_w
        (const float*)d_in[15],   // wz_b
        (const float*)d_in[16],   // wh_w
        (const float*)d_in[17],   // wh_b
        (const float*)d_in[18],   // aux_w
        (const float*)d_in[19],   // aux_b
        (float*)d_out);
}

// Round 13
// 279.904 us; speedup vs baseline: 1.2677x; 1.2677x over previous
//
#include <hip/hip_runtime.h>

typedef __bf16 bf16x8 __attribute__((ext_vector_type(8)));
typedef float f32x4 __attribute__((ext_vector_type(4)));

#define T_LEN 200
#define NB 4096

__device__ __forceinline__ f32x4 mfma16(bf16x8 a, bf16x8 b, f32x4 c) {
    return __builtin_amdgcn_mfma_f32_16x16x32_bf16(a, b, c, 0, 0, 0);
}
// raw v_rcp_f32 (1 ulp) transcendentals; saturation exact (rcp(inf)=0)
__device__ __forceinline__ float sigf(float x) {
    return __builtin_amdgcn_rcpf(1.0f + __expf(-x));
}
__device__ __forceinline__ float tanh_fast(float x) {
    return 1.0f - 2.0f * __builtin_amdgcn_rcpf(__expf(2.0f * x) + 1.0f);
}

// ---- x staging split (trunc hi + fp32 remainder lo) ----
__device__ __forceinline__ unsigned pack2(float a, float b) {
    return (__float_as_uint(a) >> 16) | (__float_as_uint(b) & 0xFFFF0000u);
}
__device__ __forceinline__ float lo_of(float v) {
    return v - __uint_as_float(__float_as_uint(v) & 0xFFFF0000u);
}
// ---- RNE hi-only publish (h-state exchanges) ----
__device__ __forceinline__ void publish_hi(unsigned short* hp, float v) {
    __bf16 h = (__bf16)v;
    *hp = __builtin_bit_cast(unsigned short, h);
}

struct Frag { bf16x8 hi, lo; };
__device__ __forceinline__ Frag make_frag(f32x4 a, f32x4 b) {
    Frag f;
    #pragma unroll
    for (int j = 0; j < 4; j++) {
        float v = a[j]; __bf16 h = (__bf16)v;
        f.hi[j] = h; f.lo[j] = (__bf16)(v - (float)h);
    }
    #pragma unroll
    for (int j = 0; j < 4; j++) {
        float v = b[j]; __bf16 h = (__bf16)v;
        f.hi[4 + j] = h; f.lo[4 + j] = (__bf16)(v - (float)h);
    }
    return f;
}
__device__ __forceinline__ bf16x8 load_w(const float* p) {   // W: bf16 RNE hi only
    f32x4 a = *(const f32x4*)p, b = *(const f32x4*)(p + 4);
    bf16x8 w;
    #pragma unroll
    for (int j = 0; j < 4; j++) { w[j] = (__bf16)a[j]; w[4 + j] = (__bf16)b[j]; }
    return w;
}
// x (hi/lo) * W
__device__ __forceinline__ f32x4 mm2(Frag a, bf16x8 w, f32x4 acc) {
    acc = mfma16(a.hi, w, acc);
    acc = mfma16(a.lo, w, acc);
    return acc;
}

// Schedule = R10/268us structure (best measured), with hi-only h exchanges.
// 8 waves: 0-3 GRU (G), 4-7 AUGRU (A). AUGRU pipelined one step.
// LDS hazards (producer -> consumer crosses >=1 barrier):
//   sX  : W by G in S1(t) [x(t+1)], R by G+A in S0(t+1)   [b_end]
//   sHG : W by G in S0(t), R by G in S1(t)                 [b_mid]
//   sScore[p]: W by G(wg0) in S1(t) (p=t&1, pre-sigmoided), R by A in S0(t+1) [b_end]
//   sHA : W by A in S0(t), R by A in S1(t)                 [b_mid]
//   sRH : W by A in S1(t), R by A in S0(t+1)/epilogue      [b_end]
__global__ __launch_bounds__(512, 2)
void dien_fused(const int* __restrict__ u_idx, const int* __restrict__ i_idx,
                const int* __restrict__ seq, const float* __restrict__ item_emb,
                const float* __restrict__ user_bias, const float* __restrict__ item_bias,
                const float* __restrict__ gw_ih, const float* __restrict__ gb_ih,
                const float* __restrict__ gw_hh, const float* __restrict__ gb_hh,
                const float* __restrict__ attn_w, const float* __restrict__ attn_b,
                const float* __restrict__ wr_w, const float* __restrict__ wr_b,
                const float* __restrict__ wz_w, const float* __restrict__ wz_b,
                const float* __restrict__ wh_w, const float* __restrict__ wh_b,
                const float* __restrict__ aux_w, const float* __restrict__ aux_b,
                float* __restrict__ out)
{
    __shared__ int sSeq[16][T_LEN];
    __shared__ __align__(16) float sTP[16][64];
    __shared__ __align__(16) unsigned short sHGhi[16][72];
    __shared__ __align__(16) unsigned short sHAhi[16][72];
    __shared__ __align__(16) unsigned short sRHhi[16][72];
    __shared__ __align__(16) unsigned short sXhi[16][72], sXlo[16][72];
    __shared__ float sScore[2][16];
    __shared__ float sParts[16][4];

    const int tid  = threadIdx.x;
    const int wave = tid >> 6;           // 0..7
    const int lane = tid & 63;
    const int c    = lane & 15;
    const int q    = lane >> 4;
    const bool isG = (wave < 4);
    const int wg   = wave & 3;
    const int dglob = wg * 16 + c;
    const int row0 = blockIdx.x * 16;

    // ---- stage seq indices ----
    for (int i = tid; i < 16 * T_LEN; i += 512) {
        int b = i / T_LEN, t = i - b * T_LEN;
        sSeq[b][t] = seq[(row0 + b) * T_LEN + t];
    }

    // ---- fm1 ----
    if (tid < 16) {
        int b = row0 + tid;
        out[b] = user_bias[u_idx[b]] + item_bias[i_idx[b]];
    }

    // ---- target_proj (16x64 fp32), threads 0..255 ----
    if (tid < 256) {
        int b  = tid >> 4;
        int d0 = (tid & 15) * 4;
        const float* erow = item_emb + (long)i_idx[row0 + b] * 64;
        float e[64];
        #pragma unroll
        for (int k4 = 0; k4 < 16; k4++) {
            f32x4 v = *(const f32x4*)(erow + k4 * 4);
            #pragma unroll
            for (int j = 0; j < 4; j++) e[k4 * 4 + j] = v[j];
        }
        #pragma unroll
        for (int dd = 0; dd < 4; dd++) {
            int d = d0 + dd;
            const float* wrow = attn_w + d * 64;
            float s = attn_b[d];
            #pragma unroll
            for (int k4 = 0; k4 < 16; k4++) {
                f32x4 wv = *(const f32x4*)(wrow + k4 * 4);
                #pragma unroll
                for (int j = 0; j < 4; j++) s += e[k4 * 4 + j] * wv[j];
            }
            sTP[b][d] = s;
        }
    }

    // ---- zero ha exchange buffer (A S1(0) reads it); prime sX with x(0) ----
    for (int i = tid; i < 16 * 72; i += 512) sHAhi[0][i] = 0;
    const int xrow = wg * 4 + (lane >> 4);   // producer row (G)
    const int xch  = lane & 15;              // 4-float chunk within row
    if (isG) {
        const float* p = item_emb + (long)seq[(row0 + xrow) * T_LEN + 0] * 64 + xch * 4;
        f32x4 v = *(const f32x4*)p;
        unsigned h01 = pack2(v[0], v[1]), h23 = pack2(v[2], v[3]);
        unsigned l01 = pack2(lo_of(v[0]), lo_of(v[1])), l23 = pack2(lo_of(v[2]), lo_of(v[3]));
        *(uint2*)&sXhi[xrow][xch * 4] = make_uint2(h01, h23);
        *(uint2*)&sXlo[xrow][xch * 4] = make_uint2(l01, l23);
    }
    __syncthreads();

    // ---- register-resident weights (bf16-hi RNE), unioned across groups ----
    // G: W[0..1]=wih_r, W[2..3]=wih_z, W[4..5]=wih_n, W[6..7]=whh_r, W[8..9]=whh_z, W[10..11]=whh_n
    // A: W[0..1]=wrx, W[2..3]=wrh, W[4..5]=wzx, W[6..7]=wzh, W[8..9]=whx, W[10..11]=whhat
    bf16x8 W[12];
    if (isG) {
        #pragma unroll
        for (int g = 0; g < 3; g++)
            #pragma unroll
            for (int s = 0; s < 2; s++) {
                W[g * 2 + s]     = load_w(gw_ih + (g * 64 + dglob) * 64 + s * 32 + q * 8);
                W[6 + g * 2 + s] = load_w(gw_hh + (g * 64 + dglob) * 64 + s * 32 + q * 8);
            }
    } else {
        #pragma unroll
        for (int s = 0; s < 2; s++) {
            const int fo = dglob * 128 + s * 32 + q * 8;
            W[0 + s]  = load_w(wr_w + fo);
            W[2 + s]  = load_w(wr_w + fo + 64);
            W[4 + s]  = load_w(wz_w + fo);
            W[6 + s]  = load_w(wz_w + fo + 64);
            W[8 + s]  = load_w(wh_w + fo);
            W[10 + s] = load_w(wh_w + fo + 64);
        }
    }

    float bA, bB, bC, bD;
    if (isG) {
        bA = gb_ih[dglob] + gb_hh[dglob];
        bB = gb_ih[64 + dglob] + gb_hh[64 + dglob];
        bC = gb_ih[128 + dglob];
        bD = gb_hh[128 + dglob];
    } else {
        bA = wr_b[dglob];
        bB = wz_b[dglob];
        bC = wh_b[dglob];
        bD = 0.0f;
    }
    const float auxwc = aux_w[dglob];

    // TP as B-fragment (G only), hi/lo
    Frag tpB0, tpB1;
    if (isG) {
        tpB0 = make_frag(*(const f32x4*)&sTP[c][q * 8], *(const f32x4*)&sTP[c][q * 8 + 4]);
        tpB1 = make_frag(*(const f32x4*)&sTP[c][32 + q * 8], *(const f32x4*)&sTP[c][32 + q * 8 + 4]);
    }

    // ---- state ----
    float hst[4] = {0.f, 0.f, 0.f, 0.f};   // G: hg(t); A: ha(t-1)
    bf16x8 fr0, fr1;                        // G: hg(t-1) hi-frags; A: scratch
    #pragma unroll
    for (int j = 0; j < 8; j++) { fr0[j] = (__bf16)0.f; fr1[j] = (__bf16)0.f; }
    f32x4 aAH = {0.f, 0.f, 0.f, 0.f};
    float z_c[4] = {0.f, 0.f, 0.f, 0.f};

    for (int t = 0; t < T_LEN; t++) {
        f32x4 xg;         // G: x(t+1) raw (global), consumed in S1
        f32x4 aAR, aAZ;   // A: r/z preactivations, live S0 -> S1

        // ================= Section 0 =================
        Frag xA0, xA1;
        xA0.hi = *(const bf16x8*)&sXhi[c][q * 8];
        xA1.hi = *(const bf16x8*)&sXhi[c][32 + q * 8];
        xA0.lo = *(const bf16x8*)&sXlo[c][q * 8];
        xA1.lo = *(const bf16x8*)&sXlo[c][32 + q * 8];

        if (isG) {
            int tn = (t + 1 < T_LEN) ? t + 1 : t;
            xg = *(const f32x4*)(item_emb + (long)sSeq[xrow][tn] * 64 + xch * 4);

            f32x4 accR = {bA, bA, bA, bA};
            accR = mm2(xA0, W[0], accR); accR = mm2(xA1, W[1], accR);
            accR = mfma16(fr0, W[6], accR); accR = mfma16(fr1, W[7], accR);
            f32x4 accZ = {bB, bB, bB, bB};
            accZ = mm2(xA0, W[2], accZ); accZ = mm2(xA1, W[3], accZ);
            accZ = mfma16(fr0, W[8], accZ); accZ = mfma16(fr1, W[9], accZ);
            f32x4 accNX = {bC, bC, bC, bC};
            accNX = mm2(xA0, W[4], accNX); accNX = mm2(xA1, W[5], accNX);
            f32x4 accNH = {bD, bD, bD, bD};
            accNH = mfma16(fr0, W[10], accNH); accNH = mfma16(fr1, W[11], accNH);

            #pragma unroll
            for (int i = 0; i < 4; i++) {
                float r = sigf(accR[i]);
                float z = sigf(accZ[i]);
                float n = tanh_fast(accNX[i] + r * accNH[i]);
                float hn = n + z * (hst[i] - n);
                hst[i] = hn;
                publish_hi(&sHGhi[q * 4 + i][dglob], hn);
            }
        } else {
            if (t > 0) {
                bf16x8 rh0 = *(const bf16x8*)&sRHhi[c][q * 8];
                bf16x8 rh1 = *(const bf16x8*)&sRHhi[c][32 + q * 8];
                aAH = mfma16(rh0, W[10], aAH); aAH = mfma16(rh1, W[11], aAH);
                #pragma unroll
                for (int i = 0; i < 4; i++) {
                    int rr = q * 4 + i;
                    float a = sScore[(t - 1) & 1][rr];   // pre-sigmoided
                    float hh = tanh_fast(aAH[i]);
                    float zz = a * z_c[i];
                    float hv = hst[i] + zz * (hh - hst[i]);
                    hst[i] = hv;
                    publish_hi(&sHAhi[rr][dglob], hv);
                }
            }
            aAR = (f32x4){bA, bA, bA, bA};
            aAR = mm2(xA0, W[0], aAR); aAR = mm2(xA1, W[1], aAR);
            aAZ = (f32x4){bB, bB, bB, bB};
            aAZ = mm2(xA0, W[4], aAZ); aAZ = mm2(xA1, W[5], aAZ);
            aAH = (f32x4){bC, bC, bC, bC};
            aAH = mm2(xA0, W[8], aAH); aAH = mm2(xA1, W[9], aAH);
        }

        __syncthreads();  // b_mid

        // ================= Section 1 =================
        if (isG) {
            fr0 = *(const bf16x8*)&sHGhi[c][q * 8];
            fr1 = *(const bf16x8*)&sHGhi[c][32 + q * 8];
            // score(t) = diag(hg(t) . tp^T) via MFMA (hg hi x tp hi/lo)
            f32x4 sc = {0.f, 0.f, 0.f, 0.f};
            sc = mfma16(fr0, tpB0.hi, sc); sc = mfma16(fr0, tpB0.lo, sc);
            sc = mfma16(fr1, tpB1.hi, sc); sc = mfma16(fr1, tpB1.lo, sc);
            if (wg == 0 && (c >> 2) == q) {
                int i = c & 3;
                float d = (i == 0) ? sc[0] : (i == 1) ? sc[1] : (i == 2) ? sc[2] : sc[3];
                sScore[t & 1][c] = sigf(d);
            }
            // stage x(t+1) pre-split into sX
            unsigned h01 = pack2(xg[0], xg[1]), h23 = pack2(xg[2], xg[3]);
            unsigned l01 = pack2(lo_of(xg[0]), lo_of(xg[1]));
            unsigned l23 = pack2(lo_of(xg[2]), lo_of(xg[3]));
            *(uint2*)&sXhi[xrow][xch * 4] = make_uint2(h01, h23);
            *(uint2*)&sXlo[xrow][xch * 4] = make_uint2(l01, l23);
        } else {
            bf16x8 ha0 = *(const bf16x8*)&sHAhi[c][q * 8];
            bf16x8 ha1 = *(const bf16x8*)&sHAhi[c][32 + q * 8];
            aAR = mfma16(ha0, W[2], aAR); aAR = mfma16(ha1, W[3], aAR);
            aAZ = mfma16(ha0, W[6], aAZ); aAZ = mfma16(ha1, W[7], aAZ);
            #pragma unroll
            for (int i = 0; i < 4; i++) {
                float r = sigf(aAR[i]);
                z_c[i]  = sigf(aAZ[i]);
                float rh = r * hst[i];
                publish_hi(&sRHhi[q * 4 + i][dglob], rh);
            }
        }

        __syncthreads();  // b_end
    }

    // ---- epilogue: A finalizes ha(T-1), writes attn_vec ----
    if (!isG) {
        bf16x8 rh0 = *(const bf16x8*)&sRHhi[c][q * 8];
        bf16x8 rh1 = *(const bf16x8*)&sRHhi[c][32 + q * 8];
        aAH = mfma16(rh0, W[10], aAH); aAH = mfma16(rh1, W[11], aAH);
        #pragma unroll
        for (int i = 0; i < 4; i++) {
            int rr = q * 4 + i;
            float a = sScore[(T_LEN - 1) & 1][rr];
            float hh = tanh_fast(aAH[i]);
            float zz = a * z_c[i];
            float hv = hst[i] + zz * (hh - hst[i]);
            out[NB + (row0 + rr) * 64 + dglob] = hv;
        }
    }

    // ---- aux_logits from hg(T-1) (G group) ----
    if (isG) {
        float pa[4];
        #pragma unroll
        for (int i = 0; i < 4; i++) pa[i] = hst[i] * auxwc;
        #pragma unroll
        for (int m = 1; m < 16; m <<= 1) {
            #pragma unroll
            for (int i = 0; i < 4; i++) pa[i] += __shfl_xor(pa[i], m, 64);
        }
        if (c == 0) {
            #pragma unroll
            for (int i = 0; i < 4; i++) sParts[q * 4 + i][wg] = pa[i];
        }
    }
    __syncthreads();
    if (tid < 16) {
        out[NB + NB * 64 + row0 + tid] =
            sParts[tid][0] + sParts[tid][1] + sParts[tid][2] + sParts[tid][3] + aux_b[0];
    }
}

extern "C" void kernel_launch(void* const* d_in, const int* in_sizes, int n_in,
                              void* d_out, int out_size, void* d_ws, size_t ws_size,
                              hipStream_t stream) {
    dien_fused<<<dim3(256), dim3(512), 0, stream>>>(
        (const int*)d_in[0],      // u_idx
        (const int*)d_in[1],      // i_idx
        (const int*)d_in[2],      // seq
        (const float*)d_in[3],    // item_emb
        (const float*)d_in[4],    // user_bias
        (const float*)d_in[5],    // item_bias
        (const float*)d_in[6],    // gru_w_ih
        (const float*)d_in[7],    // gru_b_ih
        (const float*)d_in[8],    // gru_w_hh
        (const float*)d_in[9],    // gru_b_hh
        (const float*)d_in[10],   // attn_w
        (const float*)d_in[11],   // attn_b
        (const float*)d_in[12],   // wr_w
        (const float*)d_in[13],   // wr_b
        (const float*)d_in[14],   // wz_w
        (const float*)d_in[15],   // wz_b
        (const float*)d_in[16],   // wh_w
        (const float*)d_in[17],   // wh_b
        (const float*)d_in[18],   // aux_w
        (const float*)d_in[19],   // aux_b
        (float*)d_out);
}

// Round 14
// 264.912 us; speedup vs baseline: 1.3394x; 1.0566x over previous
//
#include <hip/hip_runtime.h>

typedef __bf16 bf16x8 __attribute__((ext_vector_type(8)));
typedef float f32x4 __attribute__((ext_vector_type(4)));

#define T_LEN 200
#define NB 4096

__device__ __forceinline__ f32x4 mfma16(bf16x8 a, bf16x8 b, f32x4 c) {
    return __builtin_amdgcn_mfma_f32_16x16x32_bf16(a, b, c, 0, 0, 0);
}
// raw v_rcp_f32 (1 ulp) transcendentals; saturation exact (rcp(inf)=0)
__device__ __forceinline__ float sigf(float x) {
    return __builtin_amdgcn_rcpf(1.0f + __expf(-x));
}
__device__ __forceinline__ float tanh_fast(float x) {
    return 1.0f - 2.0f * __builtin_amdgcn_rcpf(__expf(2.0f * x) + 1.0f);
}

// ---- RNE bf16 pack of two floats -> one dword ----
__device__ __forceinline__ unsigned packRNE2(float a, float b) {
    unsigned ha = (unsigned)__builtin_bit_cast(unsigned short, (__bf16)a);
    unsigned hb = (unsigned)__builtin_bit_cast(unsigned short, (__bf16)b);
    return ha | (hb << 16);
}
// ---- RNE hi-only publish (h-state exchanges) ----
__device__ __forceinline__ void publish_hi(unsigned short* hp, float v) {
    __bf16 h = (__bf16)v;
    *hp = __builtin_bit_cast(unsigned short, h);
}

struct Frag { bf16x8 hi, lo; };
__device__ __forceinline__ Frag make_frag(f32x4 a, f32x4 b) {
    Frag f;
    #pragma unroll
    for (int j = 0; j < 4; j++) {
        float v = a[j]; __bf16 h = (__bf16)v;
        f.hi[j] = h; f.lo[j] = (__bf16)(v - (float)h);
    }
    #pragma unroll
    for (int j = 0; j < 4; j++) {
        float v = b[j]; __bf16 h = (__bf16)v;
        f.hi[4 + j] = h; f.lo[4 + j] = (__bf16)(v - (float)h);
    }
    return f;
}
__device__ __forceinline__ bf16x8 load_w(const float* p) {   // W: bf16 RNE hi only
    f32x4 a = *(const f32x4*)p, b = *(const f32x4*)(p + 4);
    bf16x8 w;
    #pragma unroll
    for (int j = 0; j < 4; j++) { w[j] = (__bf16)a[j]; w[4 + j] = (__bf16)b[j]; }
    return w;
}

// Schedule = R13 structure (best measured: 210us counter), x now bf16-RNE hi-only.
// 8 waves: 0-3 GRU (G), 4-7 AUGRU (A). AUGRU pipelined one step.
// LDS hazards (producer -> consumer crosses >=1 barrier):
//   sX  : W by G in S1(t) [x(t+1)], R by G+A in S0(t+1)   [b_end]
//   sHG : W by G in S0(t), R by G in S1(t)                 [b_mid]
//   sScore[p]: W by G(wg0) in S1(t) (p=t&1, pre-sigmoided), R by A in S0(t+1) [b_end]
//   sHA : W by A in S0(t), R by A in S1(t)                 [b_mid]
//   sRH : W by A in S1(t), R by A in S0(t+1)/epilogue      [b_end]
__global__ __launch_bounds__(512, 2)
void dien_fused(const int* __restrict__ u_idx, const int* __restrict__ i_idx,
                const int* __restrict__ seq, const float* __restrict__ item_emb,
                const float* __restrict__ user_bias, const float* __restrict__ item_bias,
                const float* __restrict__ gw_ih, const float* __restrict__ gb_ih,
                const float* __restrict__ gw_hh, const float* __restrict__ gb_hh,
                const float* __restrict__ attn_w, const float* __restrict__ attn_b,
                const float* __restrict__ wr_w, const float* __restrict__ wr_b,
                const float* __restrict__ wz_w, const float* __restrict__ wz_b,
                const float* __restrict__ wh_w, const float* __restrict__ wh_b,
                const float* __restrict__ aux_w, const float* __restrict__ aux_b,
                float* __restrict__ out)
{
    __shared__ int sSeq[16][T_LEN];
    __shared__ __align__(16) float sTP[16][64];
    __shared__ __align__(16) unsigned short sHGhi[16][72];
    __shared__ __align__(16) unsigned short sHAhi[16][72];
    __shared__ __align__(16) unsigned short sRHhi[16][72];
    __shared__ __align__(16) unsigned short sXhi[16][72];
    __shared__ float sScore[2][16];
    __shared__ float sParts[16][4];

    const int tid  = threadIdx.x;
    const int wave = tid >> 6;           // 0..7
    const int lane = tid & 63;
    const int c    = lane & 15;
    const int q    = lane >> 4;
    const bool isG = (wave < 4);
    const int wg   = wave & 3;
    const int dglob = wg * 16 + c;
    const int row0 = blockIdx.x * 16;

    // ---- stage seq indices ----
    for (int i = tid; i < 16 * T_LEN; i += 512) {
        int b = i / T_LEN, t = i - b * T_LEN;
        sSeq[b][t] = seq[(row0 + b) * T_LEN + t];
    }

    // ---- fm1 ----
    if (tid < 16) {
        int b = row0 + tid;
        out[b] = user_bias[u_idx[b]] + item_bias[i_idx[b]];
    }

    // ---- target_proj (16x64 fp32), threads 0..255 ----
    if (tid < 256) {
        int b  = tid >> 4;
        int d0 = (tid & 15) * 4;
        const float* erow = item_emb + (long)i_idx[row0 + b] * 64;
        float e[64];
        #pragma unroll
        for (int k4 = 0; k4 < 16; k4++) {
            f32x4 v = *(const f32x4*)(erow + k4 * 4);
            #pragma unroll
            for (int j = 0; j < 4; j++) e[k4 * 4 + j] = v[j];
        }
        #pragma unroll
        for (int dd = 0; dd < 4; dd++) {
            int d = d0 + dd;
            const float* wrow = attn_w + d * 64;
            float s = attn_b[d];
            #pragma unroll
            for (int k4 = 0; k4 < 16; k4++) {
                f32x4 wv = *(const f32x4*)(wrow + k4 * 4);
                #pragma unroll
                for (int j = 0; j < 4; j++) s += e[k4 * 4 + j] * wv[j];
            }
            sTP[b][d] = s;
        }
    }

    // ---- zero ha exchange buffer (A S1(0) reads it); prime sX with x(0) ----
    for (int i = tid; i < 16 * 72; i += 512) sHAhi[0][i] = 0;
    const int xrow = wg * 4 + (lane >> 4);   // producer row (G)
    const int xch  = lane & 15;              // 4-float chunk within row
    if (isG) {
        const float* p = item_emb + (long)seq[(row0 + xrow) * T_LEN + 0] * 64 + xch * 4;
        f32x4 v = *(const f32x4*)p;
        *(uint2*)&sXhi[xrow][xch * 4] =
            make_uint2(packRNE2(v[0], v[1]), packRNE2(v[2], v[3]));
    }
    __syncthreads();

    // ---- register-resident weights (bf16-hi RNE), unioned across groups ----
    // G: W[0..1]=wih_r, W[2..3]=wih_z, W[4..5]=wih_n, W[6..7]=whh_r, W[8..9]=whh_z, W[10..11]=whh_n
    // A: W[0..1]=wrx, W[2..3]=wrh, W[4..5]=wzx, W[6..7]=wzh, W[8..9]=whx, W[10..11]=whhat
    bf16x8 W[12];
    if (isG) {
        #pragma unroll
        for (int g = 0; g < 3; g++)
            #pragma unroll
            for (int s = 0; s < 2; s++) {
                W[g * 2 + s]     = load_w(gw_ih + (g * 64 + dglob) * 64 + s * 32 + q * 8);
                W[6 + g * 2 + s] = load_w(gw_hh + (g * 64 + dglob) * 64 + s * 32 + q * 8);
            }
    } else {
        #pragma unroll
        for (int s = 0; s < 2; s++) {
            const int fo = dglob * 128 + s * 32 + q * 8;
            W[0 + s]  = load_w(wr_w + fo);
            W[2 + s]  = load_w(wr_w + fo + 64);
            W[4 + s]  = load_w(wz_w + fo);
            W[6 + s]  = load_w(wz_w + fo + 64);
            W[8 + s]  = load_w(wh_w + fo);
            W[10 + s] = load_w(wh_w + fo + 64);
        }
    }

    float bA, bB, bC, bD;
    if (isG) {
        bA = gb_ih[dglob] + gb_hh[dglob];
        bB = gb_ih[64 + dglob] + gb_hh[64 + dglob];
        bC = gb_ih[128 + dglob];
        bD = gb_hh[128 + dglob];
    } else {
        bA = wr_b[dglob];
        bB = wz_b[dglob];
        bC = wh_b[dglob];
        bD = 0.0f;
    }
    const float auxwc = aux_w[dglob];

    // TP as B-fragment (G only), hi/lo (score feeds sigmoid; keep accurate)
    Frag tpB0, tpB1;
    if (isG) {
        tpB0 = make_frag(*(const f32x4*)&sTP[c][q * 8], *(const f32x4*)&sTP[c][q * 8 + 4]);
        tpB1 = make_frag(*(const f32x4*)&sTP[c][32 + q * 8], *(const f32x4*)&sTP[c][32 + q * 8 + 4]);
    }

    // ---- state ----
    float hst[4] = {0.f, 0.f, 0.f, 0.f};   // G: hg(t); A: ha(t-1)
    bf16x8 fr0, fr1;                        // G: hg(t-1) hi-frags; A: scratch
    #pragma unroll
    for (int j = 0; j < 8; j++) { fr0[j] = (__bf16)0.f; fr1[j] = (__bf16)0.f; }
    f32x4 aAH = {0.f, 0.f, 0.f, 0.f};
    float z_c[4] = {0.f, 0.f, 0.f, 0.f};

    for (int t = 0; t < T_LEN; t++) {
        f32x4 xg;         // G: x(t+1) raw (global), consumed in S1
        f32x4 aAR, aAZ;   // A: r/z preactivations, live S0 -> S1

        // ================= Section 0 =================
        bf16x8 x0 = *(const bf16x8*)&sXhi[c][q * 8];
        bf16x8 x1 = *(const bf16x8*)&sXhi[c][32 + q * 8];

        if (isG) {
            int tn = (t + 1 < T_LEN) ? t + 1 : t;
            xg = *(const f32x4*)(item_emb + (long)sSeq[xrow][tn] * 64 + xch * 4);

            f32x4 accR = {bA, bA, bA, bA};
            accR = mfma16(x0, W[0], accR); accR = mfma16(x1, W[1], accR);
            accR = mfma16(fr0, W[6], accR); accR = mfma16(fr1, W[7], accR);
            f32x4 accZ = {bB, bB, bB, bB};
            accZ = mfma16(x0, W[2], accZ); accZ = mfma16(x1, W[3], accZ);
            accZ = mfma16(fr0, W[8], accZ); accZ = mfma16(fr1, W[9], accZ);
            f32x4 accNX = {bC, bC, bC, bC};
            accNX = mfma16(x0, W[4], accNX); accNX = mfma16(x1, W[5], accNX);
            f32x4 accNH = {bD, bD, bD, bD};
            accNH = mfma16(fr0, W[10], accNH); accNH = mfma16(fr1, W[11], accNH);

            #pragma unroll
            for (int i = 0; i < 4; i++) {
                float r = sigf(accR[i]);
                float z = sigf(accZ[i]);
                float n = tanh_fast(accNX[i] + r * accNH[i]);
                float hn = n + z * (hst[i] - n);
                hst[i] = hn;
                publish_hi(&sHGhi[q * 4 + i][dglob], hn);
            }
        } else {
            if (t > 0) {
                bf16x8 rh0 = *(const bf16x8*)&sRHhi[c][q * 8];
                bf16x8 rh1 = *(const bf16x8*)&sRHhi[c][32 + q * 8];
                aAH = mfma16(rh0, W[10], aAH); aAH = mfma16(rh1, W[11], aAH);
                #pragma unroll
                for (int i = 0; i < 4; i++) {
                    int rr = q * 4 + i;
                    float a = sScore[(t - 1) & 1][rr];   // pre-sigmoided
                    float hh = tanh_fast(aAH[i]);
                    float zz = a * z_c[i];
                    float hv = hst[i] + zz * (hh - hst[i]);
                    hst[i] = hv;
                    publish_hi(&sHAhi[rr][dglob], hv);
                }
            }
            aAR = (f32x4){bA, bA, bA, bA};
            aAR = mfma16(x0, W[0], aAR); aAR = mfma16(x1, W[1], aAR);
            aAZ = (f32x4){bB, bB, bB, bB};
            aAZ = mfma16(x0, W[4], aAZ); aAZ = mfma16(x1, W[5], aAZ);
            aAH = (f32x4){bC, bC, bC, bC};
            aAH = mfma16(x0, W[8], aAH); aAH = mfma16(x1, W[9], aAH);
        }

        __syncthreads();  // b_mid

        // ================= Section 1 =================
        if (isG) {
            fr0 = *(const bf16x8*)&sHGhi[c][q * 8];
            fr1 = *(const bf16x8*)&sHGhi[c][32 + q * 8];
            // score(t) = diag(hg(t) . tp^T) via MFMA (hg hi x tp hi/lo)
            f32x4 sc = {0.f, 0.f, 0.f, 0.f};
            sc = mfma16(fr0, tpB0.hi, sc); sc = mfma16(fr0, tpB0.lo, sc);
            sc = mfma16(fr1, tpB1.hi, sc); sc = mfma16(fr1, tpB1.lo, sc);
            if (wg == 0 && (c >> 2) == q) {
                int i = c & 3;
                float d = (i == 0) ? sc[0] : (i == 1) ? sc[1] : (i == 2) ? sc[2] : sc[3];
                sScore[t & 1][c] = sigf(d);
            }
            // stage x(t+1) (RNE bf16) into sX
            *(uint2*)&sXhi[xrow][xch * 4] =
                make_uint2(packRNE2(xg[0], xg[1]), packRNE2(xg[2], xg[3]));
        } else {
            bf16x8 ha0 = *(const bf16x8*)&sHAhi[c][q * 8];
            bf16x8 ha1 = *(const bf16x8*)&sHAhi[c][32 + q * 8];
            aAR = mfma16(ha0, W[2], aAR); aAR = mfma16(ha1, W[3], aAR);
            aAZ = mfma16(ha0, W[6], aAZ); aAZ = mfma16(ha1, W[7], aAZ);
            #pragma unroll
            for (int i = 0; i < 4; i++) {
                float r = sigf(aAR[i]);
                z_c[i]  = sigf(aAZ[i]);
                float rh = r * hst[i];
                publish_hi(&sRHhi[q * 4 + i][dglob], rh);
            }
        }

        __syncthreads();  // b_end
    }

    // ---- epilogue: A finalizes ha(T-1), writes attn_vec ----
    if (!isG) {
        bf16x8 rh0 = *(const bf16x8*)&sRHhi[c][q * 8];
        bf16x8 rh1 = *(const bf16x8*)&sRHhi[c][32 + q * 8];
        aAH = mfma16(rh0, W[10], aAH); aAH = mfma16(rh1, W[11], aAH);
        #pragma unroll
        for (int i = 0; i < 4; i++) {
            int rr = q * 4 + i;
            float a = sScore[(T_LEN - 1) & 1][rr];
            float hh = tanh_fast(aAH[i]);
            float zz = a * z_c[i];
            float hv = hst[i] + zz * (hh - hst[i]);
            out[NB + (row0 + rr) * 64 + dglob] = hv;
        }
    }

    // ---- aux_logits from hg(T-1) (G group) ----
    if (isG) {
        float pa[4];
        #pragma unroll
        for (int i = 0; i < 4; i++) pa[i] = hst[i] * auxwc;
        #pragma unroll
        for (int m = 1; m < 16; m <<= 1) {
            #pragma unroll
            for (int i = 0; i < 4; i++) pa[i] += __shfl_xor(pa[i], m, 64);
        }
        if (c == 0) {
            #pragma unroll
            for (int i = 0; i < 4; i++) sParts[q * 4 + i][wg] = pa[i];
        }
    }
    __syncthreads();
    if (tid < 16) {
        out[NB + NB * 64 + row0 + tid] =
            sParts[tid][0] + sParts[tid][1] + sParts[tid][2] + sParts[tid][3] + aux_b[0];
    }
}

extern "C" void kernel_launch(void* const* d_in, const int* in_sizes, int n_in,
                              void* d_out, int out_size, void* d_ws, size_t ws_size,
                              hipStream_t stream) {
    dien_fused<<<dim3(256), dim3(512), 0, stream>>>(
        (const int*)d_in[0],      // u_idx
        (const int*)d_in[1],      // i_idx
        (const int*)d_in[2],      // seq
        (const float*)d_in[3],    // item_emb
        (const float*)d_in[4],    // user_bias
        (const float*)d_in[5],    // item_bias
        (const float*)d_in[6],    // gru_w_ih
        (const float*)d_in[7],    // gru_b_ih
        (const float*)d_in[8],    // gru_w_hh
        (const float*)d_in[9],    // gru_b_hh
        (const float*)d_in[10],   // attn_w
        (const float*)d_in[11],   // attn_b
        (const float*)d_in[12],   // wr_w
        (const float*)d_in[13],   // wr_b
        (const float*)d_in[14],   // wz_w
        (const float*)d_in[15],   // wz_b
        (const float*)d_in[16],   // wh_w
        (const float*)d_in[17],   // wh_b
        (const float*)d_in[18],   // aux_w
        (const float*)d_in[19],   // aux_b
        (float*)d_out);
}